// Round 1
// baseline (2453.569 us; speedup 1.0000x reference)
//
#include <hip/hip_runtime.h>

#define Bn 2
#define Tn 2048
#define Cn 1024
#define Hn 16
#define BTn (Bn*Tn)

typedef float4 f4;

__device__ __forceinline__ f4 ld4(const float* p) { return *(const f4*)p; }

// ---------------- pre: token-shift mixes ----------------
// xx = shift(x) - x ; out_j = x + xx * m_j   for 6 mixes
__global__ __launch_bounds__(256) void pre_kernel(
    const float* __restrict__ x,
    const float* __restrict__ mr, const float* __restrict__ mw,
    const float* __restrict__ mk, const float* __restrict__ mv,
    const float* __restrict__ ma, const float* __restrict__ mg,
    float* __restrict__ oxr, float* __restrict__ oxw, float* __restrict__ oxk,
    float* __restrict__ oxv, float* __restrict__ oxa, float* __restrict__ oxg)
{
  int i = blockIdx.x * 256 + threadIdx.x;   // float4 index; one block == one (b,t) row
  int c4 = i & 255;                          // C/4 = 256
  int bt = i >> 8;
  int t = bt & (Tn - 1);
  f4 xc = ((const f4*)x)[i];
  f4 xp = make_float4(0.f, 0.f, 0.f, 0.f);
  if (t) xp = ((const f4*)x)[i - 256];       // uniform branch (bt constant per block)
  f4 xx = make_float4(xp.x - xc.x, xp.y - xc.y, xp.z - xc.z, xp.w - xc.w);
  {
    f4 m = ((const f4*)mr)[c4]; f4 r;
    r.x = xc.x + xx.x*m.x; r.y = xc.y + xx.y*m.y; r.z = xc.z + xx.z*m.z; r.w = xc.w + xx.w*m.w;
    ((f4*)oxr)[i] = r;
  }
  {
    f4 m = ((const f4*)mw)[c4]; f4 r;
    r.x = xc.x + xx.x*m.x; r.y = xc.y + xx.y*m.y; r.z = xc.z + xx.z*m.z; r.w = xc.w + xx.w*m.w;
    ((f4*)oxw)[i] = r;
  }
  {
    f4 m = ((const f4*)mk)[c4]; f4 r;
    r.x = xc.x + xx.x*m.x; r.y = xc.y + xx.y*m.y; r.z = xc.z + xx.z*m.z; r.w = xc.w + xx.w*m.w;
    ((f4*)oxk)[i] = r;
  }
  {
    f4 m = ((const f4*)mv)[c4]; f4 r;
    r.x = xc.x + xx.x*m.x; r.y = xc.y + xx.y*m.y; r.z = xc.z + xx.z*m.z; r.w = xc.w + xx.w*m.w;
    ((f4*)oxv)[i] = r;
  }
  {
    f4 m = ((const f4*)ma)[c4]; f4 r;
    r.x = xc.x + xx.x*m.x; r.y = xc.y + xx.y*m.y; r.z = xc.z + xx.z*m.z; r.w = xc.w + xx.w*m.w;
    ((f4*)oxa)[i] = r;
  }
  {
    f4 m = ((const f4*)mg)[c4]; f4 r;
    r.x = xc.x + xx.x*m.x; r.y = xc.y + xx.y*m.y; r.z = xc.z + xx.z*m.z; r.w = xc.w + xx.w*m.w;
    ((f4*)oxg)[i] = r;
  }
}

// ---------------- gemm_nt: Y[M,N] = X[M,K] @ W[N,K]^T  (f32) ----------------
// tile 128x64, BK=16, 256 thr, micro 8x4. Requires M%128==0, N%64==0, K%16==0.
__global__ __launch_bounds__(256) void gemm_nt(
    const float* __restrict__ X, const float* __restrict__ W,
    float* __restrict__ Y, int M, int N, int K)
{
  __shared__ float As[16][132];
  __shared__ float Bs[16][68];
  int tid = threadIdx.x;
  int m0 = blockIdx.y * 128;
  int n0 = blockIdx.x * 64;
  int tx = tid & 15, ty = tid >> 4;
  int lm = tid >> 2;
  int lk = (tid & 3) * 4;
  float acc[8][4] = {};
  const float* Xa = X + (m0 + lm) * K + lk;
  const float* Xb = X + (m0 + lm + 64) * K + lk;
  const float* Wp = W + (n0 + lm) * K + lk;
  for (int k0 = 0; k0 < K; k0 += 16) {
    f4 a0 = ld4(Xa + k0);
    f4 a1 = ld4(Xb + k0);
    f4 b0 = ld4(Wp + k0);
    __syncthreads();
    As[lk+0][lm]    = a0.x; As[lk+1][lm]    = a0.y; As[lk+2][lm]    = a0.z; As[lk+3][lm]    = a0.w;
    As[lk+0][lm+64] = a1.x; As[lk+1][lm+64] = a1.y; As[lk+2][lm+64] = a1.z; As[lk+3][lm+64] = a1.w;
    Bs[lk+0][lm]    = b0.x; Bs[lk+1][lm]    = b0.y; Bs[lk+2][lm]    = b0.z; Bs[lk+3][lm]    = b0.w;
    __syncthreads();
#pragma unroll
    for (int kk = 0; kk < 16; ++kk) {
      f4 bq = *(const f4*)&Bs[kk][tx*4];
      f4 al = *(const f4*)&As[kk][ty*8];
      f4 ah = *(const f4*)&As[kk][ty*8+4];
      float aa[8] = {al.x,al.y,al.z,al.w,ah.x,ah.y,ah.z,ah.w};
      float bb[4] = {bq.x,bq.y,bq.z,bq.w};
#pragma unroll
      for (int i = 0; i < 8; ++i)
#pragma unroll
        for (int j = 0; j < 4; ++j)
          acc[i][j] = fmaf(aa[i], bb[j], acc[i][j]);
    }
  }
#pragma unroll
  for (int i = 0; i < 8; ++i) {
    int row = m0 + ty*8 + i;
#pragma unroll
    for (int j = 0; j < 4; ++j)
      Y[row * N + n0 + tx*4 + j] = acc[i][j];
  }
}

// ---------------- gemm_nn: Y[M,N] = X[M,K] @ W[K,N] (+bias, act) ----------------
// tile 64x64, BK=16, micro 4x4, guarded on N. act: 0 none, 1 tanh, 2 sigmoid.
// Requires M%64==0, K%16==0, N%4==0.
__global__ __launch_bounds__(256) void gemm_nn(
    const float* __restrict__ X, const float* __restrict__ W,
    const float* __restrict__ bias, float* __restrict__ Y,
    int M, int N, int K, int act)
{
  __shared__ float As[16][68];
  __shared__ float Bs[16][68];
  int tid = threadIdx.x;
  int m0 = blockIdx.y * 64;
  int n0 = blockIdx.x * 64;
  int tx = tid & 15, ty = tid >> 4;
  int lm = tid >> 2, lk = (tid & 3) * 4;
  int bk = tid >> 4, bn = (tid & 15) * 4;
  float acc[4][4] = {};
  for (int k0 = 0; k0 < K; k0 += 16) {
    f4 a = ld4(X + (m0 + lm) * K + k0 + lk);
    f4 b = make_float4(0.f, 0.f, 0.f, 0.f);
    if (n0 + bn < N) b = ld4(W + (k0 + bk) * N + n0 + bn);
    __syncthreads();
    As[lk+0][lm] = a.x; As[lk+1][lm] = a.y; As[lk+2][lm] = a.z; As[lk+3][lm] = a.w;
    Bs[bk][bn+0] = b.x; Bs[bk][bn+1] = b.y; Bs[bk][bn+2] = b.z; Bs[bk][bn+3] = b.w;
    __syncthreads();
#pragma unroll
    for (int kk = 0; kk < 16; ++kk) {
      f4 bq = *(const f4*)&Bs[kk][tx*4];
      f4 aq = *(const f4*)&As[kk][ty*4];
      float aa[4] = {aq.x,aq.y,aq.z,aq.w};
      float bb[4] = {bq.x,bq.y,bq.z,bq.w};
#pragma unroll
      for (int i = 0; i < 4; ++i)
#pragma unroll
        for (int j = 0; j < 4; ++j)
          acc[i][j] = fmaf(aa[i], bb[j], acc[i][j]);
    }
  }
#pragma unroll
  for (int i = 0; i < 4; ++i) {
    int row = m0 + ty*4 + i;
#pragma unroll
    for (int j = 0; j < 4; ++j) {
      int n = n0 + tx*4 + j;
      if (n < N) {
        float v = acc[i][j];
        if (bias) v += bias[n];
        if (act == 1) v = tanhf(v);
        else if (act == 2) v = 1.f / (1.f + expf(-v));
        Y[row * N + n] = v;
      }
    }
  }
}

// ---------------- prep: kk normalize, k/v blend, decay; one wave per (b,t,h) --------
__global__ __launch_bounds__(256) void prep_kernel(
    float* __restrict__ w_io,          // in: w      out: wd = exp(-exp(w))
    float* __restrict__ k_io,          // in: k0     out: k0*(1+(a-1)*k_a)
    float* __restrict__ v_io,          // in: v0x    out: v0x + (v_first-v0x)*vsig
    const float* __restrict__ a_in,    // sigmoid'ed a
    float* av_io,                      // in: vsig   out: -kk   (aliased in-place)
    const float* __restrict__ v_first,
    const float* __restrict__ k_k, const float* __restrict__ k_a,
    float* __restrict__ b_out)         // out: kk * a
{
  int gid = blockIdx.x * 256 + threadIdx.x;
  int lane = threadIdx.x & 63;
  int wv = gid >> 6;            // 0 .. B*T*H-1
  int h = wv & (Hn - 1);
  int bt = wv >> 4;
  int c = h * 64 + lane;
  int idx = bt * Cn + c;
  float k0v = k_io[idx];
  float av  = a_in[idx];
  float wvv = w_io[idx];
  float v0v = v_io[idx];
  float vfv = v_first[idx];
  float vs  = av_io[idx];
  float kk = k0v * k_k[c];
  float nr = kk * kk;
#pragma unroll
  for (int m = 32; m; m >>= 1) nr += __shfl_xor(nr, m, 64);
  kk = kk / fmaxf(sqrtf(nr), 1e-12f);
  k_io[idx] = k0v * (1.f + (av - 1.f) * k_a[c]);
  v_io[idx] = v0v + (vfv - v0v) * vs;
  w_io[idx] = expf(-expf(wvv));
  av_io[idx] = -kk;
  b_out[idx] = kk * av;
}

// ---------------- wkv: row-separable recurrence; one wave per (b,h,i) row ----------
// lane l holds state s_l (key dim). Per step: sa = <s,a>; s = s*wd + sa*b + v_i*k;
// out_i = <s,r>.
__global__ __launch_bounds__(256) void wkv_kernel(
    const float* __restrict__ r, const float* __restrict__ wd,
    const float* __restrict__ k, const float* __restrict__ v,
    const float* __restrict__ aI, const float* __restrict__ bI,
    float* __restrict__ o)
{
  int gwv = (blockIdx.x * 256 + threadIdx.x) >> 6;  // 0..2047
  int lane = threadIdx.x & 63;
  int i = gwv & 63;
  int bh = gwv >> 6;              // 0..31
  int b = bh >> 4, h = bh & 15;
  int off  = (b * Tn) * Cn + h * 64 + lane;   // col-vector element for this lane
  int offv = (b * Tn) * Cn + h * 64 + i;      // v_i scalar for this row
  int obase = offv;
  float s = 0.f;
  float wdv = wd[off], av = aI[off], bv = bI[off], kv = k[off], rv = r[off], vi = v[offv];
  for (int t = 0; t < Tn; ++t) {
    // prefetch t+1 (hides HBM/L2 latency under the reduce chain)
    float wd2 = 0.f, a2 = 0.f, b2 = 0.f, k2 = 0.f, r2 = 0.f, v2 = 0.f;
    if (t < Tn - 1) {
      int noff = off + Cn, noffv = offv + Cn;
      wd2 = wd[noff]; a2 = aI[noff]; b2 = bI[noff];
      k2 = k[noff]; r2 = r[noff]; v2 = v[noffv];
    }
    float sa = s * av;
#pragma unroll
    for (int m = 32; m; m >>= 1) sa += __shfl_xor(sa, m, 64);
    s = s * wdv + sa * bv + vi * kv;
    float ou = s * rv;
#pragma unroll
    for (int m = 32; m; m >>= 1) ou += __shfl_xor(ou, m, 64);
    if (lane == 0) o[obase + t * Cn] = ou;
    off += Cn; offv += Cn;
    wdv = wd2; av = a2; bv = b2; kv = k2; rv = r2; vi = v2;
  }
}

// ---------------- post: GroupNorm + rk*v bonus + ROSA gate + *g; block per (b,t) ----
__global__ __launch_bounds__(256) void post_kernel(
    const float* __restrict__ o_in, const float* __restrict__ r,
    const float* __restrict__ k, const float* __restrict__ v,
    const float* __restrict__ g, const float* __restrict__ lng,
    const float* __restrict__ lnb, const float* __restrict__ r_k,
    const float* __restrict__ gw, const float* __restrict__ remb,
    const int* __restrict__ ids, float* __restrict__ og)
{
  int bt = blockIdx.x;
  int tid = threadIdx.x;
  int c0 = tid * 4;                  // 4 channels/thread; 16 threads per head
  int base = bt * Cn + c0;
  f4 o4 = ld4(o_in + base);
  // GroupNorm stats over 64 channels == 16 consecutive lanes
  float sum = o4.x + o4.y + o4.z + o4.w;
  float sq  = o4.x*o4.x + o4.y*o4.y + o4.z*o4.z + o4.w*o4.w;
#pragma unroll
  for (int m = 8; m; m >>= 1) { sum += __shfl_xor(sum, m, 64); sq += __shfl_xor(sq, m, 64); }
  float mu  = sum * (1.f / 64.f);
  float var = sq * (1.f / 64.f) - mu * mu;
  float inv = rsqrtf(var + 6.4e-4f);
  f4 lg = ld4(lng + c0), lb = ld4(lnb + c0);
  f4 on;
  on.x = (o4.x - mu) * inv * lg.x + lb.x;
  on.y = (o4.y - mu) * inv * lg.y + lb.y;
  on.z = (o4.z - mu) * inv * lg.z + lb.z;
  on.w = (o4.w - mu) * inv * lg.w + lb.w;
  // per-head (r*k*r_k).sum * v bonus
  f4 r4 = ld4(r + base), k4 = ld4(k + base), v4 = ld4(v + base);
  int head = tid >> 4;
  f4 rk4 = ld4(r_k + head * 64 + (c0 & 63));
  float rk = r4.x*k4.x*rk4.x + r4.y*k4.y*rk4.y + r4.z*k4.z*rk4.z + r4.w*k4.w*rk4.w;
#pragma unroll
  for (int m = 8; m; m >>= 1) rk += __shfl_xor(rk, m, 64);
  on.x += rk * v4.x; on.y += rk * v4.y; on.z += rk * v4.z; on.w += rk * v4.w;
  // ROSA gate = mean over C of sigmoid(o * gw)
  f4 gwv = ld4(gw + c0);
  float gp = 1.f/(1.f+expf(-on.x*gwv.x)) + 1.f/(1.f+expf(-on.y*gwv.y))
           + 1.f/(1.f+expf(-on.z*gwv.z)) + 1.f/(1.f+expf(-on.w*gwv.w));
#pragma unroll
  for (int m = 32; m; m >>= 1) gp += __shfl_xor(gp, m, 64);
  __shared__ float red[4];
  if ((tid & 63) == 0) red[tid >> 6] = gp;
  __syncthreads();
  float gate = (red[0] + red[1] + red[2] + red[3]) * (1.f / 1024.f);
  int id = ids[bt]; if (id < 0) id = 0;
  f4 e4 = *(const f4*)(remb + (size_t)id * Cn + c0);
  float om = 1.f - gate;
  on.x = on.x * om + e4.x * gate;
  on.y = on.y * om + e4.y * gate;
  on.z = on.z * om + e4.z * gate;
  on.w = on.w * om + e4.w * gate;
  f4 g4 = ld4(g + base);
  f4 out4 = make_float4(on.x*g4.x, on.y*g4.y, on.z*g4.z, on.w*g4.w);
  *(f4*)(og + base) = out4;
}

// =====================================================================
extern "C" void kernel_launch(void* const* d_in, const int* in_sizes, int n_in,
                              void* d_out, int out_size, void* d_ws, size_t ws_size,
                              hipStream_t stream)
{
  const float* x   = (const float*)d_in[0];
  const float* vfi = (const float*)d_in[1];
  const int*   ids = (const int*)d_in[2];
  const float* x_r = (const float*)d_in[3];
  const float* x_w = (const float*)d_in[4];
  const float* x_k = (const float*)d_in[5];
  const float* x_v = (const float*)d_in[6];
  const float* x_a = (const float*)d_in[7];
  const float* x_g = (const float*)d_in[8];
  const float* w0  = (const float*)d_in[9];
  const float* w1  = (const float*)d_in[10];
  const float* w2  = (const float*)d_in[11];
  const float* a0  = (const float*)d_in[12];
  const float* a1  = (const float*)d_in[13];
  const float* a2  = (const float*)d_in[14];
  const float* v0  = (const float*)d_in[15];
  const float* v1  = (const float*)d_in[16];
  const float* v2  = (const float*)d_in[17];
  const float* g1  = (const float*)d_in[18];
  const float* g2  = (const float*)d_in[19];
  const float* k_k = (const float*)d_in[20];
  const float* k_a = (const float*)d_in[21];
  const float* r_k = (const float*)d_in[22];
  const float* Wr  = (const float*)d_in[23];
  const float* Wk  = (const float*)d_in[24];
  const float* Wv  = (const float*)d_in[25];
  const float* Wo  = (const float*)d_in[26];
  const float* lng = (const float*)d_in[27];
  const float* lnb = (const float*)d_in[28];
  const float* emb = (const float*)d_in[29];
  const float* gw  = (const float*)d_in[30];
  float* out = (float*)d_out;

  // workspace layout (f32): 9 big bufs (BT*C) + 4 small LoRA bufs  ~= 156 MB
  const size_t SZ = (size_t)BTn * Cn;
  float* base = (float*)d_ws;
  float* P0 = base + 0*SZ;  // xr -> w -> wd
  float* P1 = base + 1*SZ;  // xw -> k0 -> k
  float* P2 = base + 2*SZ;  // xk -> v0x -> v
  float* P3 = base + 3*SZ;  // xv -> vsig -> aIn(-kk) -> og
  float* P4 = base + 4*SZ;  // xa -> a
  float* P5 = base + 5*SZ;  // xg -> g
  float* P6 = base + 6*SZ;  // r
  float* P7 = base + 7*SZ;  // bIn (kk*a)
  float* P8 = base + 8*SZ;  // o (wkv out)
  float* S1 = base + 9*SZ;                   // t1: BT x 64
  float* S2 = S1 + (size_t)BTn * 64;         // t2: BT x 64
  float* S3 = S2 + (size_t)BTn * 64;         // t3: BT x 32
  float* S4 = S3 + (size_t)BTn * 32;         // t4: BT x 128

  dim3 blk(256);
  dim3 gnt(Cn / 64, BTn / 128);      // NT grid for 4096x1024x1024
  dim3 gnn_big(Cn / 64, BTn / 64);   // NN grid for N=1024 second-stage LoRA

  // 1) token-shift mixes
  pre_kernel<<<BTn * Cn / 1024, blk, 0, stream>>>(x, x_r, x_w, x_k, x_v, x_a, x_g,
                                                  P0, P1, P2, P3, P4, P5);
  // 2) r = xr @ Wr^T
  gemm_nt<<<gnt, blk, 0, stream>>>(P0, Wr, P6, BTn, Cn, Cn);
  // 3) w-LoRA: t1 = tanh(xw@w1);  w = w0 + t1@w2  -> P0 (xr dead)
  gemm_nn<<<dim3(1, BTn/64), blk, 0, stream>>>(P1, w1, nullptr, S1, BTn, 64, Cn, 1);
  gemm_nn<<<gnn_big, blk, 0, stream>>>(S1, w2, w0, P0, BTn, Cn, 64, 0);
  // 4) k0 = xk @ Wk^T -> P1 (xw dead)
  gemm_nt<<<gnt, blk, 0, stream>>>(P2, Wk, P1, BTn, Cn, Cn);
  // 5) v-LoRA first stage reads xv BEFORE xv is overwritten
  gemm_nn<<<dim3(1, BTn/64), blk, 0, stream>>>(P3, v1, nullptr, S3, BTn, 32, Cn, 0);
  // 6) v0x = xv @ Wv^T -> P2 (xk dead)
  gemm_nt<<<gnt, blk, 0, stream>>>(P3, Wv, P2, BTn, Cn, Cn);
  // 7) vsig = sigmoid(v0 + t3@v2) -> P3 (xv dead)
  gemm_nn<<<gnn_big, blk, 0, stream>>>(S3, v2, v0, P3, BTn, Cn, 32, 2);
  // 8) a-LoRA: t2 = xa@a1; a = sigmoid(a0 + t2@a2) -> P4
  gemm_nn<<<dim3(1, BTn/64), blk, 0, stream>>>(P4, a1, nullptr, S2, BTn, 64, Cn, 0);
  gemm_nn<<<gnn_big, blk, 0, stream>>>(S2, a2, a0, P4, BTn, Cn, 64, 2);
  // 9) g: t4 = sigmoid(xg@g1); g = t4@g2 -> P5
  gemm_nn<<<dim3(2, BTn/64), blk, 0, stream>>>(P5, g1, nullptr, S4, BTn, 128, Cn, 2);
  gemm_nn<<<gnn_big, blk, 0, stream>>>(S4, g2, nullptr, P5, BTn, Cn, 128, 0);
  // 10) prep -> wd(P0), k(P1), v(P2), aIn(P3), bIn(P7)
  prep_kernel<<<BTn * Hn / 4, blk, 0, stream>>>(P0, P1, P2, P4, P3, vfi, k_k, k_a, P7);
  // 11) wkv -> o(P8).  2048 row-chains, 4 waves/block.
  wkv_kernel<<<Bn * Hn * 64 / 4, blk, 0, stream>>>(P6, P0, P1, P2, P3, P7, P8);
  // 12) post (GN + bonus + ROSA + *g) -> og(P3)
  post_kernel<<<BTn, blk, 0, stream>>>(P8, P6, P1, P2, P5, lng, lnb, r_k, gw, emb, ids, P3);
  // 13) out = og @ Wo^T
  gemm_nt<<<gnt, blk, 0, stream>>>(P3, Wo, out, BTn, Cn, Cn);
}

// Round 2
// 1657.151 us; speedup vs baseline: 1.4806x; 1.4806x over previous
//
#include <hip/hip_runtime.h>

#define Bn 2
#define Tn 2048
#define Cn 1024
#define Hn 16
#define BTn (Bn*Tn)
#define LCH 16

typedef float4 f4;

__device__ __forceinline__ f4 ld4(const float* p) { return *(const f4*)p; }

// ---- async global->LDS helpers (wave-uniform LDS base + lane*size) ----
__device__ __forceinline__ void gload_lds16(const float* g, float* l) {
  __builtin_amdgcn_global_load_lds(
      (const __attribute__((address_space(1))) unsigned int*)g,
      (__attribute__((address_space(3))) unsigned int*)l, 16, 0, 0);
}
__device__ __forceinline__ void gload_lds4(const float* g, float* l) {
  __builtin_amdgcn_global_load_lds(
      (const __attribute__((address_space(1))) unsigned int*)g,
      (__attribute__((address_space(3))) unsigned int*)l, 4, 0, 0);
}

// ---- 64-lane all-reduce sum on the VALU pipe (DPP + permlane swaps) ----
template <int CTRL>
__device__ __forceinline__ float dpp_add_f(float x) {
  int t = __builtin_amdgcn_update_dpp(0, __float_as_int(x), CTRL, 0xf, 0xf, true);
  return x + __int_as_float(t);
}

__device__ __forceinline__ float allsum64(float x) {
  x = dpp_add_f<0xB1>(x);    // quad_perm [1,0,3,2]  : xor 1
  x = dpp_add_f<0x4E>(x);    // quad_perm [2,3,0,1]  : xor 2
  x = dpp_add_f<0x141>(x);   // row_half_mirror      : xor 4 (after 1,2)
  x = dpp_add_f<0x140>(x);   // row_mirror           : xor 8 (after 1,2,4)
#if defined(__has_builtin) && __has_builtin(__builtin_amdgcn_permlane16_swap)
  {
    auto pr = __builtin_amdgcn_permlane16_swap(__float_as_uint(x), __float_as_uint(x), false, false);
    x = __uint_as_float(pr[0]) + __uint_as_float(pr[1]);   // xor 16
  }
#else
  x += __shfl_xor(x, 16, 64);
#endif
#if defined(__has_builtin) && __has_builtin(__builtin_amdgcn_permlane32_swap)
  {
    auto pr = __builtin_amdgcn_permlane32_swap(__float_as_uint(x), __float_as_uint(x), false, false);
    x = __uint_as_float(pr[0]) + __uint_as_float(pr[1]);   // xor 32
  }
#else
  x += __shfl_xor(x, 32, 64);
#endif
  return x;
}

// ---------------- pre: token-shift mixes ----------------
__global__ __launch_bounds__(256) void pre_kernel(
    const float* __restrict__ x,
    const float* __restrict__ mr, const float* __restrict__ mw,
    const float* __restrict__ mk, const float* __restrict__ mv,
    const float* __restrict__ ma, const float* __restrict__ mg,
    float* __restrict__ oxr, float* __restrict__ oxw, float* __restrict__ oxk,
    float* __restrict__ oxv, float* __restrict__ oxa, float* __restrict__ oxg)
{
  int i = blockIdx.x * 256 + threadIdx.x;
  int c4 = i & 255;
  int bt = i >> 8;
  int t = bt & (Tn - 1);
  f4 xc = ((const f4*)x)[i];
  f4 xp = make_float4(0.f, 0.f, 0.f, 0.f);
  if (t) xp = ((const f4*)x)[i - 256];
  f4 xx = make_float4(xp.x - xc.x, xp.y - xc.y, xp.z - xc.z, xp.w - xc.w);
  {
    f4 m = ((const f4*)mr)[c4]; f4 r;
    r.x = xc.x + xx.x*m.x; r.y = xc.y + xx.y*m.y; r.z = xc.z + xx.z*m.z; r.w = xc.w + xx.w*m.w;
    ((f4*)oxr)[i] = r;
  }
  {
    f4 m = ((const f4*)mw)[c4]; f4 r;
    r.x = xc.x + xx.x*m.x; r.y = xc.y + xx.y*m.y; r.z = xc.z + xx.z*m.z; r.w = xc.w + xx.w*m.w;
    ((f4*)oxw)[i] = r;
  }
  {
    f4 m = ((const f4*)mk)[c4]; f4 r;
    r.x = xc.x + xx.x*m.x; r.y = xc.y + xx.y*m.y; r.z = xc.z + xx.z*m.z; r.w = xc.w + xx.w*m.w;
    ((f4*)oxk)[i] = r;
  }
  {
    f4 m = ((const f4*)mv)[c4]; f4 r;
    r.x = xc.x + xx.x*m.x; r.y = xc.y + xx.y*m.y; r.z = xc.z + xx.z*m.z; r.w = xc.w + xx.w*m.w;
    ((f4*)oxv)[i] = r;
  }
  {
    f4 m = ((const f4*)ma)[c4]; f4 r;
    r.x = xc.x + xx.x*m.x; r.y = xc.y + xx.y*m.y; r.z = xc.z + xx.z*m.z; r.w = xc.w + xx.w*m.w;
    ((f4*)oxa)[i] = r;
  }
  {
    f4 m = ((const f4*)mg)[c4]; f4 r;
    r.x = xc.x + xx.x*m.x; r.y = xc.y + xx.y*m.y; r.z = xc.z + xx.z*m.z; r.w = xc.w + xx.w*m.w;
    ((f4*)oxg)[i] = r;
  }
}

// ---------------- gemm_nt: Y[M,N] = X[M,K] @ W[N,K]^T  (f32) ----------------
__global__ __launch_bounds__(256) void gemm_nt(
    const float* __restrict__ X, const float* __restrict__ W,
    float* __restrict__ Y, int M, int N, int K)
{
  __shared__ float As[16][132];
  __shared__ float Bs[16][68];
  int tid = threadIdx.x;
  int m0 = blockIdx.y * 128;
  int n0 = blockIdx.x * 64;
  int tx = tid & 15, ty = tid >> 4;
  int lm = tid >> 2;
  int lk = (tid & 3) * 4;
  float acc[8][4] = {};
  const float* Xa = X + (m0 + lm) * K + lk;
  const float* Xb = X + (m0 + lm + 64) * K + lk;
  const float* Wp = W + (n0 + lm) * K + lk;
  for (int k0 = 0; k0 < K; k0 += 16) {
    f4 a0 = ld4(Xa + k0);
    f4 a1 = ld4(Xb + k0);
    f4 b0 = ld4(Wp + k0);
    __syncthreads();
    As[lk+0][lm]    = a0.x; As[lk+1][lm]    = a0.y; As[lk+2][lm]    = a0.z; As[lk+3][lm]    = a0.w;
    As[lk+0][lm+64] = a1.x; As[lk+1][lm+64] = a1.y; As[lk+2][lm+64] = a1.z; As[lk+3][lm+64] = a1.w;
    Bs[lk+0][lm]    = b0.x; Bs[lk+1][lm]    = b0.y; Bs[lk+2][lm]    = b0.z; Bs[lk+3][lm]    = b0.w;
    __syncthreads();
#pragma unroll
    for (int kk = 0; kk < 16; ++kk) {
      f4 bq = *(const f4*)&Bs[kk][tx*4];
      f4 al = *(const f4*)&As[kk][ty*8];
      f4 ah = *(const f4*)&As[kk][ty*8+4];
      float aa[8] = {al.x,al.y,al.z,al.w,ah.x,ah.y,ah.z,ah.w};
      float bb[4] = {bq.x,bq.y,bq.z,bq.w};
#pragma unroll
      for (int i = 0; i < 8; ++i)
#pragma unroll
        for (int j = 0; j < 4; ++j)
          acc[i][j] = fmaf(aa[i], bb[j], acc[i][j]);
    }
  }
#pragma unroll
  for (int i = 0; i < 8; ++i) {
    int row = m0 + ty*8 + i;
#pragma unroll
    for (int j = 0; j < 4; ++j)
      Y[row * N + n0 + tx*4 + j] = acc[i][j];
  }
}

// ---------------- gemm_nn: Y[M,N] = X[M,K] @ W[K,N] (+bias, act) ----------------
__global__ __launch_bounds__(256) void gemm_nn(
    const float* __restrict__ X, const float* __restrict__ W,
    const float* __restrict__ bias, float* __restrict__ Y,
    int M, int N, int K, int act)
{
  __shared__ float As[16][68];
  __shared__ float Bs[16][68];
  int tid = threadIdx.x;
  int m0 = blockIdx.y * 64;
  int n0 = blockIdx.x * 64;
  int tx = tid & 15, ty = tid >> 4;
  int lm = tid >> 2, lk = (tid & 3) * 4;
  int bk = tid >> 4, bn = (tid & 15) * 4;
  float acc[4][4] = {};
  for (int k0 = 0; k0 < K; k0 += 16) {
    f4 a = ld4(X + (m0 + lm) * K + k0 + lk);
    f4 b = make_float4(0.f, 0.f, 0.f, 0.f);
    if (n0 + bn < N) b = ld4(W + (k0 + bk) * N + n0 + bn);
    __syncthreads();
    As[lk+0][lm] = a.x; As[lk+1][lm] = a.y; As[lk+2][lm] = a.z; As[lk+3][lm] = a.w;
    Bs[bk][bn+0] = b.x; Bs[bk][bn+1] = b.y; Bs[bk][bn+2] = b.z; Bs[bk][bn+3] = b.w;
    __syncthreads();
#pragma unroll
    for (int kk = 0; kk < 16; ++kk) {
      f4 bq = *(const f4*)&Bs[kk][tx*4];
      f4 aq = *(const f4*)&As[kk][ty*4];
      float aa[4] = {aq.x,aq.y,aq.z,aq.w};
      float bb[4] = {bq.x,bq.y,bq.z,bq.w};
#pragma unroll
      for (int i = 0; i < 4; ++i)
#pragma unroll
        for (int j = 0; j < 4; ++j)
          acc[i][j] = fmaf(aa[i], bb[j], acc[i][j]);
    }
  }
#pragma unroll
  for (int i = 0; i < 4; ++i) {
    int row = m0 + ty*4 + i;
#pragma unroll
    for (int j = 0; j < 4; ++j) {
      int n = n0 + tx*4 + j;
      if (n < N) {
        float v = acc[i][j];
        if (bias) v += bias[n];
        if (act == 1) v = tanhf(v);
        else if (act == 2) v = 1.f / (1.f + expf(-v));
        Y[row * N + n] = v;
      }
    }
  }
}

// ---------------- prep: kk normalize, k/v blend, decay; one wave per (b,t,h) --------
__global__ __launch_bounds__(256) void prep_kernel(
    float* __restrict__ w_io, float* __restrict__ k_io, float* __restrict__ v_io,
    const float* __restrict__ a_in, float* av_io,
    const float* __restrict__ v_first,
    const float* __restrict__ k_k, const float* __restrict__ k_a,
    float* __restrict__ b_out)
{
  int gid = blockIdx.x * 256 + threadIdx.x;
  int lane = threadIdx.x & 63;
  int wv = gid >> 6;
  int h = wv & (Hn - 1);
  int bt = wv >> 4;
  int c = h * 64 + lane;
  int idx = bt * Cn + c;
  float k0v = k_io[idx];
  float av  = a_in[idx];
  float wvv = w_io[idx];
  float v0v = v_io[idx];
  float vfv = v_first[idx];
  float vs  = av_io[idx];
  float kk = k0v * k_k[c];
  float nr = allsum64(kk * kk);
  kk = kk / fmaxf(sqrtf(nr), 1e-12f);
  k_io[idx] = k0v * (1.f + (av - 1.f) * k_a[c]);
  v_io[idx] = v0v + (vfv - v0v) * vs;
  w_io[idx] = expf(-expf(wvv));
  av_io[idx] = -kk;
  b_out[idx] = kk * av;
}

// ---------------- wkv: 4 rows of one (b,h) per block; LDS chunk double-buffer ------
// 512 blocks x 4 waves. Wave w owns row i = grp*4 + w; lane = key index j.
// Per step: sa = <s,a> (DPP allsum); s = s*wd + sa*b + v_i*k; out = <s,r>.
__global__ __launch_bounds__(256) void wkv_kernel(
    const float* __restrict__ r, const float* __restrict__ wd,
    const float* __restrict__ k, const float* __restrict__ v,
    const float* __restrict__ aI, const float* __restrict__ bI,
    float* __restrict__ o)
{
  __shared__ float sh[2][5][LCH][64];   // wd,k,a,b,r  : 2*5*16*64*4B = 40 KB
  __shared__ float shv[2][LCH][4];      // v for this block's 4 rows
  int tid = threadIdx.x;
  int w = tid >> 6, lane = tid & 63;
  // XCD swizzle: physical p -> (bh, grp) s.t. all 16 blocks of a (b,h) share an XCD
  int p = blockIdx.x;
  int bh  = (p & 7) | (((p >> 3) & 3) << 3);   // 0..31
  int grp = p >> 5;                             // 0..15
  int i0 = grp << 2;
  int b = bh >> 4, h = bh & 15;
  size_t base0 = (size_t)(b * Tn) * Cn + h * 64;
  const float* gs0 = wd + base0;
  const float* gs1 = k  + base0;
  const float* gs2 = aI + base0;
  const float* gs3 = bI + base0;
  const float* gs4 = r  + base0;
  const float* gv  = v  + base0 + i0;
  float* op = o + base0 + i0 + w;
  // staging map: lane l loads (t_local = w*4 + l/16, col = (l&15)*4) as 16B
  int tl = (w << 2) + (lane >> 4);
  int cc = (lane & 15) << 2;
  int vt = lane >> 2, vi = lane & 3;            // v staging (wave 0 only)

  {   // stage chunk 0 -> buffer 0
    size_t go = (size_t)tl * Cn + cc;
    gload_lds16(gs0 + go, &sh[0][0][w << 2][0]);
    gload_lds16(gs1 + go, &sh[0][1][w << 2][0]);
    gload_lds16(gs2 + go, &sh[0][2][w << 2][0]);
    gload_lds16(gs3 + go, &sh[0][3][w << 2][0]);
    gload_lds16(gs4 + go, &sh[0][4][w << 2][0]);
    if (w == 0) gload_lds4(gv + (size_t)vt * Cn + vi, &shv[0][0][0]);
  }
  __syncthreads();

  float s = 0.f;
  for (int c = 0; c < Tn / LCH; ++c) {
    int bb = c & 1;
    if (c + 1 < Tn / LCH) {   // prefetch next chunk into the other buffer
      size_t go = (size_t)((c + 1) * LCH + tl) * Cn + cc;
      gload_lds16(gs0 + go, &sh[bb ^ 1][0][w << 2][0]);
      gload_lds16(gs1 + go, &sh[bb ^ 1][1][w << 2][0]);
      gload_lds16(gs2 + go, &sh[bb ^ 1][2][w << 2][0]);
      gload_lds16(gs3 + go, &sh[bb ^ 1][3][w << 2][0]);
      gload_lds16(gs4 + go, &sh[bb ^ 1][4][w << 2][0]);
      if (w == 0) gload_lds4(gv + (size_t)((c + 1) * LCH + vt) * Cn + vi, &shv[bb ^ 1][0][0]);
    }
    float cwd = sh[bb][0][0][lane], ckk = sh[bb][1][0][lane], ca = sh[bb][2][0][lane],
          cb  = sh[bb][3][0][lane], crr = sh[bb][4][0][lane], cv = shv[bb][0][w];
#pragma unroll
    for (int tt = 0; tt < LCH; ++tt) {
      float nwd, nk, na, nb, nr, nv;
      if (tt + 1 < LCH) {   // depth-1 register prefetch from LDS
        nwd = sh[bb][0][tt + 1][lane]; nk = sh[bb][1][tt + 1][lane];
        na  = sh[bb][2][tt + 1][lane]; nb = sh[bb][3][tt + 1][lane];
        nr  = sh[bb][4][tt + 1][lane]; nv = shv[bb][tt + 1][w];
      }
      float sa  = allsum64(s * ca);          // critical chain: VALU-only reduce
      float pre = fmaf(s, cwd, cv * ckk);    // off-chain while reduce runs
      s = fmaf(sa, cb, pre);
      float ou = allsum64(s * crr);          // feeds store only (off next-step chain)
      if (lane == 0) op[(size_t)(c * LCH + tt) * Cn] = ou;
      if (tt + 1 < LCH) { cwd = nwd; ckk = nk; ca = na; cb = nb; crr = nr; cv = nv; }
    }
    __syncthreads();
  }
}

// ---------------- post: GroupNorm + rk*v bonus + ROSA gate + *g; block per (b,t) ----
__global__ __launch_bounds__(256) void post_kernel(
    const float* __restrict__ o_in, const float* __restrict__ r,
    const float* __restrict__ k, const float* __restrict__ v,
    const float* __restrict__ g, const float* __restrict__ lng,
    const float* __restrict__ lnb, const float* __restrict__ r_k,
    const float* __restrict__ gw, const float* __restrict__ remb,
    const int* __restrict__ ids, float* __restrict__ og)
{
  int bt = blockIdx.x;
  int tid = threadIdx.x;
  int c0 = tid * 4;
  int base = bt * Cn + c0;
  f4 o4 = ld4(o_in + base);
  float sum = o4.x + o4.y + o4.z + o4.w;
  float sq  = o4.x*o4.x + o4.y*o4.y + o4.z*o4.z + o4.w*o4.w;
#pragma unroll
  for (int m = 8; m; m >>= 1) { sum += __shfl_xor(sum, m, 64); sq += __shfl_xor(sq, m, 64); }
  float mu  = sum * (1.f / 64.f);
  float var = sq * (1.f / 64.f) - mu * mu;
  float inv = rsqrtf(var + 6.4e-4f);
  f4 lg = ld4(lng + c0), lb = ld4(lnb + c0);
  f4 on;
  on.x = (o4.x - mu) * inv * lg.x + lb.x;
  on.y = (o4.y - mu) * inv * lg.y + lb.y;
  on.z = (o4.z - mu) * inv * lg.z + lb.z;
  on.w = (o4.w - mu) * inv * lg.w + lb.w;
  f4 r4 = ld4(r + base), k4 = ld4(k + base), v4 = ld4(v + base);
  int head = tid >> 4;
  f4 rk4 = ld4(r_k + head * 64 + (c0 & 63));
  float rk = r4.x*k4.x*rk4.x + r4.y*k4.y*rk4.y + r4.z*k4.z*rk4.z + r4.w*k4.w*rk4.w;
#pragma unroll
  for (int m = 8; m; m >>= 1) rk += __shfl_xor(rk, m, 64);
  on.x += rk * v4.x; on.y += rk * v4.y; on.z += rk * v4.z; on.w += rk * v4.w;
  f4 gwv = ld4(gw + c0);
  float gp = 1.f/(1.f+expf(-on.x*gwv.x)) + 1.f/(1.f+expf(-on.y*gwv.y))
           + 1.f/(1.f+expf(-on.z*gwv.z)) + 1.f/(1.f+expf(-on.w*gwv.w));
#pragma unroll
  for (int m = 32; m; m >>= 1) gp += __shfl_xor(gp, m, 64);
  __shared__ float red[4];
  if ((tid & 63) == 0) red[tid >> 6] = gp;
  __syncthreads();
  float gate = (red[0] + red[1] + red[2] + red[3]) * (1.f / 1024.f);
  int id = ids[bt]; if (id < 0) id = 0;
  f4 e4 = *(const f4*)(remb + (size_t)id * Cn + c0);
  float om = 1.f - gate;
  on.x = on.x * om + e4.x * gate;
  on.y = on.y * om + e4.y * gate;
  on.z = on.z * om + e4.z * gate;
  on.w = on.w * om + e4.w * gate;
  f4 g4 = ld4(g + base);
  f4 out4 = make_float4(on.x*g4.x, on.y*g4.y, on.z*g4.z, on.w*g4.w);
  *(f4*)(og + base) = out4;
}

// =====================================================================
extern "C" void kernel_launch(void* const* d_in, const int* in_sizes, int n_in,
                              void* d_out, int out_size, void* d_ws, size_t ws_size,
                              hipStream_t stream)
{
  const float* x   = (const float*)d_in[0];
  const float* vfi = (const float*)d_in[1];
  const int*   ids = (const int*)d_in[2];
  const float* x_r = (const float*)d_in[3];
  const float* x_w = (const float*)d_in[4];
  const float* x_k = (const float*)d_in[5];
  const float* x_v = (const float*)d_in[6];
  const float* x_a = (const float*)d_in[7];
  const float* x_g = (const float*)d_in[8];
  const float* w0  = (const float*)d_in[9];
  const float* w1  = (const float*)d_in[10];
  const float* w2  = (const float*)d_in[11];
  const float* a0  = (const float*)d_in[12];
  const float* a1  = (const float*)d_in[13];
  const float* a2  = (const float*)d_in[14];
  const float* v0  = (const float*)d_in[15];
  const float* v1  = (const float*)d_in[16];
  const float* v2  = (const float*)d_in[17];
  const float* g1  = (const float*)d_in[18];
  const float* g2  = (const float*)d_in[19];
  const float* k_k = (const float*)d_in[20];
  const float* k_a = (const float*)d_in[21];
  const float* r_k = (const float*)d_in[22];
  const float* Wr  = (const float*)d_in[23];
  const float* Wk  = (const float*)d_in[24];
  const float* Wv  = (const float*)d_in[25];
  const float* Wo  = (const float*)d_in[26];
  const float* lng = (const float*)d_in[27];
  const float* lnb = (const float*)d_in[28];
  const float* emb = (const float*)d_in[29];
  const float* gw  = (const float*)d_in[30];
  float* out = (float*)d_out;

  const size_t SZ = (size_t)BTn * Cn;
  float* base = (float*)d_ws;
  float* P0 = base + 0*SZ;  // xr -> w -> wd
  float* P1 = base + 1*SZ;  // xw -> k0 -> k
  float* P2 = base + 2*SZ;  // xk -> v0x -> v
  float* P3 = base + 3*SZ;  // xv -> vsig -> aIn(-kk) -> og
  float* P4 = base + 4*SZ;  // xa -> a
  float* P5 = base + 5*SZ;  // xg -> g
  float* P6 = base + 6*SZ;  // r
  float* P7 = base + 7*SZ;  // bIn (kk*a)
  float* P8 = base + 8*SZ;  // o (wkv out)
  float* S1 = base + 9*SZ;
  float* S2 = S1 + (size_t)BTn * 64;
  float* S3 = S2 + (size_t)BTn * 64;
  float* S4 = S3 + (size_t)BTn * 32;

  dim3 blk(256);
  dim3 gnt(Cn / 64, BTn / 128);
  dim3 gnn_big(Cn / 64, BTn / 64);

  pre_kernel<<<BTn * Cn / 1024, blk, 0, stream>>>(x, x_r, x_w, x_k, x_v, x_a, x_g,
                                                  P0, P1, P2, P3, P4, P5);
  gemm_nt<<<gnt, blk, 0, stream>>>(P0, Wr, P6, BTn, Cn, Cn);
  gemm_nn<<<dim3(1, BTn/64), blk, 0, stream>>>(P1, w1, nullptr, S1, BTn, 64, Cn, 1);
  gemm_nn<<<gnn_big, blk, 0, stream>>>(S1, w2, w0, P0, BTn, Cn, 64, 0);
  gemm_nt<<<gnt, blk, 0, stream>>>(P2, Wk, P1, BTn, Cn, Cn);
  gemm_nn<<<dim3(1, BTn/64), blk, 0, stream>>>(P3, v1, nullptr, S3, BTn, 32, Cn, 0);
  gemm_nt<<<gnt, blk, 0, stream>>>(P3, Wv, P2, BTn, Cn, Cn);
  gemm_nn<<<gnn_big, blk, 0, stream>>>(S3, v2, v0, P3, BTn, Cn, 32, 2);
  gemm_nn<<<dim3(1, BTn/64), blk, 0, stream>>>(P4, a1, nullptr, S2, BTn, 64, Cn, 0);
  gemm_nn<<<gnn_big, blk, 0, stream>>>(S2, a2, a0, P4, BTn, Cn, 64, 2);
  gemm_nn<<<dim3(2, BTn/64), blk, 0, stream>>>(P5, g1, nullptr, S4, BTn, 128, Cn, 2);
  gemm_nn<<<gnn_big, blk, 0, stream>>>(S4, g2, nullptr, P5, BTn, Cn, 128, 0);
  prep_kernel<<<BTn * Hn / 4, blk, 0, stream>>>(P0, P1, P2, P4, P3, vfi, k_k, k_a, P7);
  // wkv: 512 blocks x 256 thr (4 rows of one (b,h) per block)
  wkv_kernel<<<512, blk, 0, stream>>>(P6, P0, P1, P2, P3, P7, P8);
  post_kernel<<<BTn, blk, 0, stream>>>(P8, P6, P1, P2, P5, lng, lnb, r_k, gw, emb, ids, P3);
  gemm_nt<<<gnt, blk, 0, stream>>>(P3, Wo, out, BTn, Cn, Cn);
}